// Round 2
// baseline (279.736 us; speedup 1.0000x reference)
//
#include <hip/hip_runtime.h>
#include <stdint.h>

#define B_      32
#define T_IN_   512
#define N_      543
#define C_      3
#define NEW_T_  426     // int(512/1.2)
#define JF_     53      // max(1, 426//8)
#define NC_     (N_*C_)             // 1629
#define XOUT_   (B_*NEW_T_*NC_)     // 22206528
#define TF_     6                   // frames chained per block
#define NCH_    ((NEW_T_ + TF_ - 1) / TF_)   // 71

#define MODE_INT   0
#define MODE_BYTE  1
#define MODE_FLOAT 2

__device__ __forceinline__ bool read_flag(const void* p, int mode, int idx) {
    if (mode == MODE_BYTE)  return ((const uint8_t*)p)[idx] != 0;
    if (mode == MODE_FLOAT) return ((const float*)p)[idx]   != 0.0f;
    return ((const int*)p)[idx] != 0;
}

// One block per batch. Builds per-(b,t): 4 frame indices + 4 weights for pd[b,t],
// jitter value (0 at t=0), and writes the mask output.
__global__ __launch_bounds__(512) void prep_kernel(
    const void* __restrict__ maskp,
    const void* __restrict__ keepp,
    const float* __restrict__ bjit,
    float* __restrict__ out_mask,
    int4*  __restrict__ wsF,
    float4* __restrict__ wsW,
    float* __restrict__ wsJ)
{
    const int b = blockIdx.x;
    const int tid = threadIdx.x;

    __shared__ int flags[6];       // [mask: f32,byte] [keep: f32,byte] (slots 2,1,5,4)
    __shared__ int s_mode_mask, s_mode_keep;
    if (tid < 6) flags[tid] = 0;
    __syncthreads();
    if (tid < 64) {
        uint32_t vm = ((const uint32_t*)maskp)[tid];
        uint32_t vk = ((const uint32_t*)keepp)[tid];
        if (vm == 0x3F800000u)      atomicOr(&flags[2], 1);
        else if (vm > 1u)           atomicOr(&flags[1], 1);
        if (vk == 0x3F800000u)      atomicOr(&flags[5], 1);
        else if (vk > 1u)           atomicOr(&flags[4], 1);
    }
    __syncthreads();
    if (tid == 0) {
        s_mode_mask = flags[2] ? MODE_FLOAT : (flags[1] ? MODE_BYTE : MODE_INT);
        s_mode_keep = flags[5] ? MODE_FLOAT : (flags[4] ? MODE_BYTE : MODE_INT);
    }
    __syncthreads();
    const int mmode = s_mode_mask, kmode = s_mode_keep;

    __shared__ int sk[512];
    __shared__ int ps[512];
    __shared__ int kept[NEW_T_];

    int kv = 0;
    if (tid < NEW_T_) kv = read_flag(keepp, kmode, b*NEW_T_ + tid) ? 1 : 0;
    sk[tid] = (tid < NEW_T_) ? kv : 0;
    ps[tid] = sk[tid];
    __syncthreads();
    // Hillis-Steele inclusive prefix sum over 512 entries
    for (int off = 1; off < 512; off <<= 1) {
        int v = (tid >= off) ? ps[tid - off] : 0;
        __syncthreads();
        ps[tid] += v;
        __syncthreads();
    }
    const int K = ps[NEW_T_ - 1];
    if (tid < NEW_T_ && kv) kept[ps[tid] - 1] = tid;  // kept indices, ascending
    __syncthreads();

    if (tid < NEW_T_) {
        const int t = tid;
        const float RATX = (float)(511.0 / 425.0);   // (T_IN-1)/(NEW_T-1), f32 like jnp
        // y-resample coeff for this t
        float st = (float)t * RATX;
        int i0 = (int)floorf(st);
        if (i0 < 0) i0 = 0; if (i0 > T_IN_ - 2) i0 = T_IN_ - 2;
        float w = st - (float)i0;

        int4 F; float4 W;
        if (kv) {
            F = make_int4(i0, i0 + 1, 0, 1);
            W = make_float4(1.0f - w, w, 0.0f, 0.0f);
        } else {
            float s = ((float)t * (float)(K - 1)) / 425.0f;
            int r0 = (int)floorf(s);
            if (r0 < 0) r0 = 0; if (r0 > K - 2) r0 = K - 2;
            float f = s - (float)r0;
            int j0 = kept[r0], j1 = kept[r0 + 1];
            float s0 = (float)j0 * RATX;
            int a0 = (int)floorf(s0);
            if (a0 < 0) a0 = 0; if (a0 > T_IN_ - 2) a0 = T_IN_ - 2;
            float w0 = s0 - (float)a0;
            float s1 = (float)j1 * RATX;
            int a1 = (int)floorf(s1);
            if (a1 < 0) a1 = 0; if (a1 > T_IN_ - 2) a1 = T_IN_ - 2;
            float w1 = s1 - (float)a1;
            F = make_int4(a0, a0 + 1, a1, a1 + 1);
            W = make_float4((1.0f - f) * (1.0f - w0), (1.0f - f) * w0,
                            f * (1.0f - w1),          f * w1);
        }
        const int bt = b * NEW_T_ + t;
        wsF[bt] = F;
        wsW[bt] = W;

        // jitter: linresample(base_jitter*0.02, NEW_T)
        const float RATJ = (float)(52.0 / 425.0);
        float sj = (float)t * RATJ;
        int ji = (int)floorf(sj);
        if (ji < 0) ji = 0; if (ji > JF_ - 2) ji = JF_ - 2;
        float jf = sj - (float)ji;
        float b0 = bjit[b*JF_ + ji]     * 0.02f;
        float b1 = bjit[b*JF_ + ji + 1] * 0.02f;
        float jv = b0 * (1.0f - jf) + b1 * jf;
        if (t == 0) jv = 0.0f;  // x[:, :1] untouched by jitter
        wsJ[bt] = jv;

        // mask output: mask[:, nidx] & keep
        float mn = (float)t * (float)(512.0 / 426.0);
        int nidx = (int)floorf(mn);
        if (nidx > T_IN_ - 1) nidx = T_IN_ - 1;
        bool mo = read_flag(maskp, mmode, b*T_IN_ + nidx) && (kv != 0);
        out_mask[bt] = mo ? 1.0f : 0.0f;
    }
}

// Compute pd (post-drop interpolated frame) for this thread's e-slice.
// e_k = tid + 256*k, k = 0..6 (k=6 valid only for tid < NC_-1536 = 93).
// Zero-weight-tap skip: branch is block-uniform (all lanes share bt).
__device__ __forceinline__ void compute_pd(float pd[7], const float* __restrict__ xb,
                                           int4 F, float4 W, int tid) {
    const float* p0 = xb + (uint32_t)F.x * NC_ + tid;
    const float* p1 = xb + (uint32_t)F.y * NC_ + tid;
    const bool four = (W.z != 0.0f) || (W.w != 0.0f);
    if (four) {
        const float* p2 = xb + (uint32_t)F.z * NC_ + tid;
        const float* p3 = xb + (uint32_t)F.w * NC_ + tid;
        #pragma unroll
        for (int k = 0; k < 6; k++)
            pd[k] = W.x * p0[256*k] + W.y * p1[256*k] + W.z * p2[256*k] + W.w * p3[256*k];
        pd[6] = (tid < NC_ - 1536) ?
            (W.x * p0[1536] + W.y * p1[1536] + W.z * p2[1536] + W.w * p3[1536]) : 0.0f;
    } else {
        #pragma unroll
        for (int k = 0; k < 6; k++)
            pd[k] = W.x * p0[256*k] + W.y * p1[256*k];
        pd[6] = (tid < NC_ - 1536) ? (W.x * p0[1536] + W.y * p1[1536]) : 0.0f;
    }
}

// One block per (b, chunk of TF_ consecutive frames). Each thread owns a fixed
// e-slice; pd of the previous frame is carried in registers across the chain,
// so each frame's taps are loaded exactly once.
__global__ __launch_bounds__(256) void main_kernel(
    const float* __restrict__ x,
    const float* __restrict__ noise,
    const float* __restrict__ spat,
    const int4*  __restrict__ wsF,
    const float4* __restrict__ wsW,
    const float* __restrict__ wsJ,
    float* __restrict__ out)
{
    const int b   = blockIdx.y;
    const int t0  = blockIdx.x * TF_;
    const int tid = threadIdx.x;
    const float* xb = x + (size_t)b * (T_IN_ * NC_);

    // spatial noise: same for every frame in the chunk — load once
    float sp[7];
    {
        const float* spb = spat + b * NC_ + tid;
        #pragma unroll
        for (int k = 0; k < 6; k++) sp[k] = spb[256*k];
        sp[6] = (tid < NC_ - 1536) ? spb[1536] : 0.0f;
    }

    // prologue: pd of frame t0-1 (t0==0: jitter is 0 there, value unused)
    float pdp[7];
    {
        const int tp = (t0 > 0) ? (t0 - 1) : 0;
        const int bt = b * NEW_T_ + tp;
        int4 F = wsF[bt]; float4 W = wsW[bt];
        compute_pd(pdp, xb, F, W, tid);
    }

    const int tend = (t0 + TF_ < NEW_T_) ? (t0 + TF_) : NEW_T_;
    for (int t = t0; t < tend; t++) {
        const int bt = b * NEW_T_ + t;
        int4 F = wsF[bt]; float4 W = wsW[bt];
        float jv = wsJ[bt];

        float pd[7];
        compute_pd(pd, xb, F, W, tid);

        const float* nz = noise + (size_t)bt * NC_ + tid;
        float*       op = out   + (size_t)bt * NC_ + tid;
        #pragma unroll
        for (int k = 0; k < 6; k++) {
            float r = pd[k] + (pd[k] - pdp[k]) * jv + nz[256*k] * 0.01f + sp[k] * 0.005f;
            op[256*k] = r;
            pdp[k] = pd[k];
        }
        if (tid < NC_ - 1536) {
            float r = pd[6] + (pd[6] - pdp[6]) * jv + nz[1536] * 0.01f + sp[6] * 0.005f;
            op[1536] = r;
        }
        pdp[6] = pd[6];
    }
}

extern "C" void kernel_launch(void* const* d_in, const int* in_sizes, int n_in,
                              void* d_out, int out_size, void* d_ws, size_t ws_size,
                              hipStream_t stream) {
    const float* x    = (const float*)d_in[0];
    const void*  mask = d_in[1];
    const void*  keep = d_in[2];
    const float* bjit = (const float*)d_in[3];
    const float* noise = (const float*)d_in[4];
    const float* spat  = (const float*)d_in[5];
    float* out = (float*)d_out;

    // workspace carve
    char* ws = (char*)d_ws;
    int4*   wsF = (int4*)ws;                           // 13632*16 = 218112 B
    float4* wsW = (float4*)(ws + 218112);              // 218112 B
    float*  wsJ = (float*)(ws + 436224);               // 54528 B

    prep_kernel<<<B_, 512, 0, stream>>>(mask, keep, bjit,
                                        out + XOUT_, wsF, wsW, wsJ);
    dim3 grid(NCH_, B_);
    main_kernel<<<grid, 256, 0, stream>>>(x, noise, spat, wsF, wsW, wsJ, out);
}

// Round 3
// 273.331 us; speedup vs baseline: 1.0234x; 1.0234x over previous
//
#include <hip/hip_runtime.h>
#include <stdint.h>

#define B_      32
#define T_IN_   512
#define N_      543
#define C_      3
#define NEW_T_  426     // int(512/1.2)
#define JF_     53      // max(1, 426//8)
#define NC_     (N_*C_)             // 1629
#define XOUT_   (B_*NEW_T_*NC_)     // 22206528
#define NGROUP_ (XOUT_/4)           // 5551632 (exact)

#define MODE_INT   0
#define MODE_BYTE  1
#define MODE_FLOAT 2

// 16-byte vector with only 4-byte alignment guarantee (x frame stride = 1629
// floats, odd -> tap/spat pointers are 4B-aligned only). gfx950 supports
// unaligned global vector access; clang emits global_load_dwordx4.
typedef float f4u __attribute__((vector_size(16), aligned(4)));

__device__ __forceinline__ bool read_flag(const void* p, int mode, int idx) {
    if (mode == MODE_BYTE)  return ((const uint8_t*)p)[idx] != 0;
    if (mode == MODE_FLOAT) return ((const float*)p)[idx]   != 0.0f;
    return ((const int*)p)[idx] != 0;
}

// One block per batch. Builds per-(b,t): 4 frame indices + 4 weights for pd[b,t],
// jitter value (0 at t=0), and writes the mask output.
// Kept frames get F=(i0,i0+1,i0,i0+1), W=(1-w,w,0,0): main stays branchless,
// duplicate taps hit the same cache lines (no extra HBM traffic), and
// 0*x contributes exact +0 -> bit-identical result.
__global__ __launch_bounds__(512) void prep_kernel(
    const void* __restrict__ maskp,
    const void* __restrict__ keepp,
    const float* __restrict__ bjit,
    float* __restrict__ out_mask,
    int4*  __restrict__ wsF,
    float4* __restrict__ wsW,
    float* __restrict__ wsJ)
{
    const int b = blockIdx.x;
    const int tid = threadIdx.x;

    __shared__ int flags[6];       // [mask: f32,byte] [keep: f32,byte] (slots 2,1,5,4)
    __shared__ int s_mode_mask, s_mode_keep;
    if (tid < 6) flags[tid] = 0;
    __syncthreads();
    if (tid < 64) {
        uint32_t vm = ((const uint32_t*)maskp)[tid];
        uint32_t vk = ((const uint32_t*)keepp)[tid];
        if (vm == 0x3F800000u)      atomicOr(&flags[2], 1);
        else if (vm > 1u)           atomicOr(&flags[1], 1);
        if (vk == 0x3F800000u)      atomicOr(&flags[5], 1);
        else if (vk > 1u)           atomicOr(&flags[4], 1);
    }
    __syncthreads();
    if (tid == 0) {
        s_mode_mask = flags[2] ? MODE_FLOAT : (flags[1] ? MODE_BYTE : MODE_INT);
        s_mode_keep = flags[5] ? MODE_FLOAT : (flags[4] ? MODE_BYTE : MODE_INT);
    }
    __syncthreads();
    const int mmode = s_mode_mask, kmode = s_mode_keep;

    __shared__ int sk[512];
    __shared__ int ps[512];
    __shared__ int kept[NEW_T_];

    int kv = 0;
    if (tid < NEW_T_) kv = read_flag(keepp, kmode, b*NEW_T_ + tid) ? 1 : 0;
    sk[tid] = (tid < NEW_T_) ? kv : 0;
    ps[tid] = sk[tid];
    __syncthreads();
    // Hillis-Steele inclusive prefix sum over 512 entries
    for (int off = 1; off < 512; off <<= 1) {
        int v = (tid >= off) ? ps[tid - off] : 0;
        __syncthreads();
        ps[tid] += v;
        __syncthreads();
    }
    const int K = ps[NEW_T_ - 1];
    if (tid < NEW_T_ && kv) kept[ps[tid] - 1] = tid;  // kept indices, ascending
    __syncthreads();

    if (tid < NEW_T_) {
        const int t = tid;
        const float RATX = (float)(511.0 / 425.0);   // (T_IN-1)/(NEW_T-1), f32 like jnp
        // y-resample coeff for this t
        float st = (float)t * RATX;
        int i0 = (int)floorf(st);
        if (i0 < 0) i0 = 0; if (i0 > T_IN_ - 2) i0 = T_IN_ - 2;
        float w = st - (float)i0;

        int4 F; float4 W;
        if (kv) {
            F = make_int4(i0, i0 + 1, i0, i0 + 1);
            W = make_float4(1.0f - w, w, 0.0f, 0.0f);
        } else {
            float s = ((float)t * (float)(K - 1)) / 425.0f;
            int r0 = (int)floorf(s);
            if (r0 < 0) r0 = 0; if (r0 > K - 2) r0 = K - 2;
            float f = s - (float)r0;
            int j0 = kept[r0], j1 = kept[r0 + 1];
            float s0 = (float)j0 * RATX;
            int a0 = (int)floorf(s0);
            if (a0 < 0) a0 = 0; if (a0 > T_IN_ - 2) a0 = T_IN_ - 2;
            float w0 = s0 - (float)a0;
            float s1 = (float)j1 * RATX;
            int a1 = (int)floorf(s1);
            if (a1 < 0) a1 = 0; if (a1 > T_IN_ - 2) a1 = T_IN_ - 2;
            float w1 = s1 - (float)a1;
            F = make_int4(a0, a0 + 1, a1, a1 + 1);
            W = make_float4((1.0f - f) * (1.0f - w0), (1.0f - f) * w0,
                            f * (1.0f - w1),          f * w1);
        }
        const int bt = b * NEW_T_ + t;
        wsF[bt] = F;
        wsW[bt] = W;

        // jitter: linresample(base_jitter*0.02, NEW_T)
        const float RATJ = (float)(52.0 / 425.0);
        float sj = (float)t * RATJ;
        int ji = (int)floorf(sj);
        if (ji < 0) ji = 0; if (ji > JF_ - 2) ji = JF_ - 2;
        float jf = sj - (float)ji;
        float b0 = bjit[b*JF_ + ji]     * 0.02f;
        float b1 = bjit[b*JF_ + ji + 1] * 0.02f;
        float jv = b0 * (1.0f - jf) + b1 * jf;
        if (t == 0) jv = 0.0f;  // x[:, :1] untouched by jitter
        wsJ[bt] = jv;

        // mask output: mask[:, nidx] & keep
        float mn = (float)t * (float)(512.0 / 426.0);
        int nidx = (int)floorf(mn);
        if (nidx > T_IN_ - 1) nidx = T_IN_ - 1;
        bool mo = read_flag(maskp, mmode, b*T_IN_ + nidx) && (kv != 0);
        out_mask[bt] = mo ? 1.0f : 0.0f;
    }
}

// One thread per 4 consecutive output floats. All streams use 16B vector
// loads (dwordx4) to maximize bytes-in-flight per VMEM queue slot.
__global__ __launch_bounds__(256) void main_kernel(
    const float* __restrict__ x,
    const float* __restrict__ noise,
    const float* __restrict__ spat,
    const int4*  __restrict__ wsF,
    const float4* __restrict__ wsW,
    const float* __restrict__ wsJ,
    float* __restrict__ out)
{
    uint32_t g = blockIdx.x * 256u + threadIdx.x;
    if (g >= (uint32_t)NGROUP_) return;
    uint32_t flat = g * 4u;
    uint32_t bt = flat / (uint32_t)NC_;
    uint32_t e  = flat - bt * (uint32_t)NC_;

    if (e <= (uint32_t)(NC_ - 4)) {
        // all 4 elements share (b,t)
        uint32_t b = bt / (uint32_t)NEW_T_;
        const float* xb = x + (size_t)b * (T_IN_ * NC_);
        int4  F  = wsF[bt];  float4 W  = wsW[bt];
        uint32_t pbt = bt ? bt - 1u : 0u;
        int4  FP = wsF[pbt]; float4 WP = wsW[pbt];
        float jv = wsJ[bt];

        // 8 tap loads, 16B each, issued back-to-back (branchless)
        f4u t0 = *(const f4u*)(xb + (uint32_t)F.x  * NC_ + e);
        f4u t1 = *(const f4u*)(xb + (uint32_t)F.y  * NC_ + e);
        f4u t2 = *(const f4u*)(xb + (uint32_t)F.z  * NC_ + e);
        f4u t3 = *(const f4u*)(xb + (uint32_t)F.w  * NC_ + e);
        f4u q0 = *(const f4u*)(xb + (uint32_t)FP.x * NC_ + e);
        f4u q1 = *(const f4u*)(xb + (uint32_t)FP.y * NC_ + e);
        f4u q2 = *(const f4u*)(xb + (uint32_t)FP.z * NC_ + e);
        f4u q3 = *(const f4u*)(xb + (uint32_t)FP.w * NC_ + e);
        f4u nz = *(const f4u*)(noise + flat);
        f4u sp = *(const f4u*)(spat + b * NC_ + e);

        f4u a  = W.x  * t0 + W.y  * t1 + W.z  * t2 + W.w  * t3;
        f4u ap = WP.x * q0 + WP.y * q1 + WP.z * q2 + WP.w * q3;
        f4u r  = a + (a - ap) * jv + nz * 0.01f + sp * 0.005f;
        *(f4u*)(out + flat) = r;
    } else {
        // frame-boundary group (~0.25% of groups): per-element scalar path
        #pragma unroll
        for (int i = 0; i < 4; i++) {
            uint32_t fl  = flat + i;
            uint32_t bt2 = fl / (uint32_t)NC_;
            uint32_t e2  = fl - bt2 * (uint32_t)NC_;
            uint32_t b2  = bt2 / (uint32_t)NEW_T_;
            const float* xb = x + (size_t)b2 * (T_IN_ * NC_);
            int4  F  = wsF[bt2];  float4 W  = wsW[bt2];
            uint32_t pbt = bt2 ? bt2 - 1u : 0u;
            int4  FP = wsF[pbt];  float4 WP = wsW[pbt];
            float jv = wsJ[bt2];
            float a  = W.x  * xb[(uint32_t)F.x  * NC_ + e2] + W.y  * xb[(uint32_t)F.y  * NC_ + e2]
                     + W.z  * xb[(uint32_t)F.z  * NC_ + e2] + W.w  * xb[(uint32_t)F.w  * NC_ + e2];
            float ap = WP.x * xb[(uint32_t)FP.x * NC_ + e2] + WP.y * xb[(uint32_t)FP.y * NC_ + e2]
                     + WP.z * xb[(uint32_t)FP.z * NC_ + e2] + WP.w * xb[(uint32_t)FP.w * NC_ + e2];
            out[fl] = a + (a - ap) * jv + noise[fl] * 0.01f + spat[b2 * NC_ + e2] * 0.005f;
        }
    }
}

extern "C" void kernel_launch(void* const* d_in, const int* in_sizes, int n_in,
                              void* d_out, int out_size, void* d_ws, size_t ws_size,
                              hipStream_t stream) {
    const float* x    = (const float*)d_in[0];
    const void*  mask = d_in[1];
    const void*  keep = d_in[2];
    const float* bjit = (const float*)d_in[3];
    const float* noise = (const float*)d_in[4];
    const float* spat  = (const float*)d_in[5];
    float* out = (float*)d_out;

    // workspace carve
    char* ws = (char*)d_ws;
    int4*   wsF = (int4*)ws;                           // 13632*16 = 218112 B
    float4* wsW = (float4*)(ws + 218112);              // 218112 B
    float*  wsJ = (float*)(ws + 436224);               // 54528 B

    prep_kernel<<<B_, 512, 0, stream>>>(mask, keep, bjit,
                                        out + XOUT_, wsF, wsW, wsJ);
    const int nblk = (NGROUP_ + 255) / 256;
    main_kernel<<<nblk, 256, 0, stream>>>(x, noise, spat, wsF, wsW, wsJ, out);
}

// Round 4
// 270.300 us; speedup vs baseline: 1.0349x; 1.0112x over previous
//
#include <hip/hip_runtime.h>
#include <stdint.h>

#define B_      32
#define T_IN_   512
#define N_      543
#define C_      3
#define NEW_T_  426     // int(512/1.2)
#define JF_     53      // max(1, 426//8)
#define NC_     (N_*C_)             // 1629
#define XOUT_   (B_*NEW_T_*NC_)     // 22206528
#define NFR_    (B_*NEW_T_)         // 13632 frames
#define GPF_    408                 // groups per frame: ceil(1629/4)
#define TOTG_   (NFR_*GPF_)         // 5,561,856 frame-local groups
#define G_      4                   // chunks per thread
#define NBLK_   5432                // ceil(TOTG_ / (256*G_))

#define MODE_INT   0
#define MODE_BYTE  1
#define MODE_FLOAT 2

// 16-byte vector, 4-byte alignment (frame stride 1629 floats is odd).
typedef float f4u __attribute__((vector_size(16), aligned(4)));

__device__ __forceinline__ bool read_flag(const void* p, int mode, int idx) {
    if (mode == MODE_BYTE)  return ((const uint8_t*)p)[idx] != 0;
    if (mode == MODE_FLOAT) return ((const float*)p)[idx]   != 0.0f;
    return ((const int*)p)[idx] != 0;
}

// One block per batch. Builds per-(b,t): 4 frame indices + 4 weights for pd[b,t],
// jitter value (0 at t=0), and writes the mask output.
// Kept frames get F=(i0,i0+1,i0,i0+1), W=(1-w,w,0,0): main stays branchless,
// duplicate taps hit the same cache lines, 0*x adds exact +0.
__global__ __launch_bounds__(512) void prep_kernel(
    const void* __restrict__ maskp,
    const void* __restrict__ keepp,
    const float* __restrict__ bjit,
    float* __restrict__ out_mask,
    int4*  __restrict__ wsF,
    float4* __restrict__ wsW,
    float* __restrict__ wsJ)
{
    const int b = blockIdx.x;
    const int tid = threadIdx.x;

    __shared__ int flags[6];
    __shared__ int s_mode_mask, s_mode_keep;
    if (tid < 6) flags[tid] = 0;
    __syncthreads();
    if (tid < 64) {
        uint32_t vm = ((const uint32_t*)maskp)[tid];
        uint32_t vk = ((const uint32_t*)keepp)[tid];
        if (vm == 0x3F800000u)      atomicOr(&flags[2], 1);
        else if (vm > 1u)           atomicOr(&flags[1], 1);
        if (vk == 0x3F800000u)      atomicOr(&flags[5], 1);
        else if (vk > 1u)           atomicOr(&flags[4], 1);
    }
    __syncthreads();
    if (tid == 0) {
        s_mode_mask = flags[2] ? MODE_FLOAT : (flags[1] ? MODE_BYTE : MODE_INT);
        s_mode_keep = flags[5] ? MODE_FLOAT : (flags[4] ? MODE_BYTE : MODE_INT);
    }
    __syncthreads();
    const int mmode = s_mode_mask, kmode = s_mode_keep;

    __shared__ int sk[512];
    __shared__ int ps[512];
    __shared__ int kept[NEW_T_];

    int kv = 0;
    if (tid < NEW_T_) kv = read_flag(keepp, kmode, b*NEW_T_ + tid) ? 1 : 0;
    sk[tid] = (tid < NEW_T_) ? kv : 0;
    ps[tid] = sk[tid];
    __syncthreads();
    for (int off = 1; off < 512; off <<= 1) {
        int v = (tid >= off) ? ps[tid - off] : 0;
        __syncthreads();
        ps[tid] += v;
        __syncthreads();
    }
    const int K = ps[NEW_T_ - 1];
    if (tid < NEW_T_ && kv) kept[ps[tid] - 1] = tid;
    __syncthreads();

    if (tid < NEW_T_) {
        const int t = tid;
        const float RATX = (float)(511.0 / 425.0);
        float st = (float)t * RATX;
        int i0 = (int)floorf(st);
        if (i0 < 0) i0 = 0; if (i0 > T_IN_ - 2) i0 = T_IN_ - 2;
        float w = st - (float)i0;

        int4 F; float4 W;
        if (kv) {
            F = make_int4(i0, i0 + 1, i0, i0 + 1);
            W = make_float4(1.0f - w, w, 0.0f, 0.0f);
        } else {
            float s = ((float)t * (float)(K - 1)) / 425.0f;
            int r0 = (int)floorf(s);
            if (r0 < 0) r0 = 0; if (r0 > K - 2) r0 = K - 2;
            float f = s - (float)r0;
            int j0 = kept[r0], j1 = kept[r0 + 1];
            float s0 = (float)j0 * RATX;
            int a0 = (int)floorf(s0);
            if (a0 < 0) a0 = 0; if (a0 > T_IN_ - 2) a0 = T_IN_ - 2;
            float w0 = s0 - (float)a0;
            float s1 = (float)j1 * RATX;
            int a1 = (int)floorf(s1);
            if (a1 < 0) a1 = 0; if (a1 > T_IN_ - 2) a1 = T_IN_ - 2;
            float w1 = s1 - (float)a1;
            F = make_int4(a0, a0 + 1, a1, a1 + 1);
            W = make_float4((1.0f - f) * (1.0f - w0), (1.0f - f) * w0,
                            f * (1.0f - w1),          f * w1);
        }
        const int bt = b * NEW_T_ + t;
        wsF[bt] = F;
        wsW[bt] = W;

        const float RATJ = (float)(52.0 / 425.0);
        float sj = (float)t * RATJ;
        int ji = (int)floorf(sj);
        if (ji < 0) ji = 0; if (ji > JF_ - 2) ji = JF_ - 2;
        float jf = sj - (float)ji;
        float b0 = bjit[b*JF_ + ji]     * 0.02f;
        float b1 = bjit[b*JF_ + ji + 1] * 0.02f;
        float jv = b0 * (1.0f - jf) + b1 * jf;
        if (t == 0) jv = 0.0f;
        wsJ[bt] = jv;

        float mn = (float)t * (float)(512.0 / 426.0);
        int nidx = (int)floorf(mn);
        if (nidx > T_IN_ - 1) nidx = T_IN_ - 1;
        bool mo = read_flag(maskp, mmode, b*T_IN_ + nidx) && (kv != 0);
        out_mask[bt] = mo ? 1.0f : 0.0f;
    }
}

// G_ frame-local groups per thread, strided S apart (coalescing preserved).
// Explicit 3 phases: ws loads -> 40x16B data loads (all in flight) -> compute.
// amdgpu_waves_per_eu(2,8) lifts the VGPR cap so the batch stays in registers.
__global__ __launch_bounds__(256) __attribute__((amdgpu_waves_per_eu(2, 8)))
void main_kernel(
    const float* __restrict__ x,
    const float* __restrict__ noise,
    const float* __restrict__ spat,
    const int4*  __restrict__ wsF,
    const float4* __restrict__ wsW,
    const float* __restrict__ wsJ,
    float* __restrict__ out)
{
    const uint32_t S = NBLK_ * 256u;
    const uint32_t g0 = blockIdx.x * 256u + threadIdx.x;

    int4   F[G_], FP[G_];
    float4 W[G_], WP[G_];
    float  JV[G_];
    uint32_t E0[G_], BT[G_], BB[G_];
    bool   VA[G_];

    // Phase A: indices + ws loads (L2-hot, 436 KB total)
    #pragma unroll
    for (int k = 0; k < G_; k++) {
        uint32_t gid = g0 + (uint32_t)k * S;
        bool v = gid < (uint32_t)TOTG_;
        VA[k] = v;
        uint32_t gc = v ? gid : 0u;
        uint32_t bt = (uint32_t)(((uint64_t)gc * 673720361ull) >> 38);   // /408 exact
        uint32_t j  = gc - bt * (uint32_t)GPF_;
        uint32_t e0 = j * 4u; if (e0 > (uint32_t)(NC_ - 4)) e0 = (uint32_t)(NC_ - 4);
        uint32_t b  = (uint32_t)(((uint64_t)bt * 161313326ull) >> 36);   // /426 exact
        uint32_t pbt = bt ? bt - 1u : 0u;
        BT[k] = bt; BB[k] = b; E0[k] = e0;
        F[k]  = wsF[bt];  W[k]  = wsW[bt];
        FP[k] = wsF[pbt]; WP[k] = wsW[pbt];
        JV[k] = wsJ[bt];
    }

    // Phase B: all bulk loads issued back-to-back
    f4u T0[G_], T1[G_], T2[G_], T3[G_], Q0[G_], Q1[G_], Q2[G_], Q3[G_], NZ[G_], SP[G_];
    #pragma unroll
    for (int k = 0; k < G_; k++) {
        const float* xb = x + (size_t)BB[k] * (T_IN_ * NC_);
        const uint32_t e0 = E0[k];
        T0[k] = *(const f4u*)(xb + (uint32_t)F[k].x  * NC_ + e0);
        T1[k] = *(const f4u*)(xb + (uint32_t)F[k].y  * NC_ + e0);
        T2[k] = *(const f4u*)(xb + (uint32_t)F[k].z  * NC_ + e0);
        T3[k] = *(const f4u*)(xb + (uint32_t)F[k].w  * NC_ + e0);
        Q0[k] = *(const f4u*)(xb + (uint32_t)FP[k].x * NC_ + e0);
        Q1[k] = *(const f4u*)(xb + (uint32_t)FP[k].y * NC_ + e0);
        Q2[k] = *(const f4u*)(xb + (uint32_t)FP[k].z * NC_ + e0);
        Q3[k] = *(const f4u*)(xb + (uint32_t)FP[k].w * NC_ + e0);
        NZ[k] = *(const f4u*)(noise + (size_t)BT[k] * NC_ + e0);
        SP[k] = *(const f4u*)(spat  + (size_t)BB[k] * NC_ + e0);
    }

    // Phase C: compute + store (overlapping tail lanes write identical values)
    #pragma unroll
    for (int k = 0; k < G_; k++) {
        if (!VA[k]) continue;
        f4u a  = W[k].x  * T0[k] + W[k].y  * T1[k] + W[k].z  * T2[k] + W[k].w  * T3[k];
        f4u ap = WP[k].x * Q0[k] + WP[k].y * Q1[k] + WP[k].z * Q2[k] + WP[k].w * Q3[k];
        f4u r  = a + (a - ap) * JV[k] + NZ[k] * 0.01f + SP[k] * 0.005f;
        *(f4u*)(out + (size_t)BT[k] * NC_ + E0[k]) = r;
    }
}

extern "C" void kernel_launch(void* const* d_in, const int* in_sizes, int n_in,
                              void* d_out, int out_size, void* d_ws, size_t ws_size,
                              hipStream_t stream) {
    const float* x    = (const float*)d_in[0];
    const void*  mask = d_in[1];
    const void*  keep = d_in[2];
    const float* bjit = (const float*)d_in[3];
    const float* noise = (const float*)d_in[4];
    const float* spat  = (const float*)d_in[5];
    float* out = (float*)d_out;

    char* ws = (char*)d_ws;
    int4*   wsF = (int4*)ws;                           // 218112 B
    float4* wsW = (float4*)(ws + 218112);              // 218112 B
    float*  wsJ = (float*)(ws + 436224);               // 54528 B

    prep_kernel<<<B_, 512, 0, stream>>>(mask, keep, bjit,
                                        out + XOUT_, wsF, wsW, wsJ);
    main_kernel<<<NBLK_, 256, 0, stream>>>(x, noise, spat, wsF, wsW, wsJ, out);
}